// Round 21
// baseline (231.770 us; speedup 1.0000x reference)
//
#include <hip/hip_runtime.h>
#include <hip/hip_bf16.h>

// Problem constants (match reference)
#define B_DIM 8192
#define D_DIM 1024
#define N_DIM 4096
#define TAU_INV 5.0f

typedef __bf16 bf16x8 __attribute__((ext_vector_type(8)));
typedef __bf16 bf16x4 __attribute__((ext_vector_type(4)));
typedef float  f32x4  __attribute__((ext_vector_type(4)));

// ---------------------------------------------------------------------------
__device__ __forceinline__ void gld_lds16(const void* g, void* l) {
  __builtin_amdgcn_global_load_lds((const __attribute__((address_space(1))) void*)g,
                                   (__attribute__((address_space(3))) void*)l,
                                   16, 0, 0);
}
__device__ __forceinline__ float fast_rcp(float x) {
  return __builtin_amdgcn_rcpf(x);
}
#define MFMA(a, b, c) __builtin_amdgcn_mfma_f32_16x16x32_bf16((a), (b), (c), 0, 0, 0)

// ---------------------------------------------------------------------------
// prep_x: x (f32 [B,D]) -> xh (bf16). Single-term bf16 verified round 10.
__global__ void prep_x(const float* __restrict__ x, __bf16* __restrict__ xh) {
  const int i = blockIdx.x * blockDim.x + threadIdx.x;
  const int base = i * 4;
  const float4 v = *reinterpret_cast<const float4*>(x + base);
  bf16x4 h;
  h[0] = (__bf16)v.x; h[1] = (__bf16)v.y; h[2] = (__bf16)v.z; h[3] = (__bf16)v.w;
  *reinterpret_cast<bf16x4*>(xh + base) = h;
}

// ---------------------------------------------------------------------------
// prep_w: W (f32 [D,N]) -> wht (bf16 [N,D]) transposed
__global__ void prep_w(const float* __restrict__ W, __bf16* __restrict__ wht) {
  __shared__ float tile[32][33];
  const int tn = blockIdx.x & 127;
  const int tk = blockIdx.x >> 7;
  const int tx = threadIdx.x & 31;
  const int ty = threadIdx.x >> 5;
#pragma unroll
  for (int r = 0; r < 4; ++r) {
    const int k = tk * 32 + ty + r * 8;
    tile[ty + r * 8][tx] = W[(size_t)k * N_DIM + tn * 32 + tx];
  }
  __syncthreads();
#pragma unroll
  for (int r = 0; r < 4; ++r) {
    const int nn = tn * 32 + ty + r * 8;
    const int kk = tk * 32 + tx;
    wht[(size_t)nn * D_DIM + kk] = (__bf16)tile[tx][ty + r * 8];
  }
}

// ---------------------------------------------------------------------------
// Fused GEMM, A-direct variant: 128x256 tile, BK=32, K=1024 single-term
// bf16, 8 waves (2Mx4N), wave tile 64x64 (acc 64 VGPR). A fragments load
// DIRECTLY from global bf16 into registers (per K-step the block's A slice
// is 8 KB -> L1-resident; 4-way wave sharing hits L1), issued one K-step
// ahead — removes A's LDS write+read (-45% LDS traffic) and the cvt VALU
// chain from the loop. B keeps gld_lds + rotation swizzle (0 conflicts
// measured) dbuf; LDS = 32 KB. Single barrier per K-step. nt epilogue.
#define BM 128
#define BN 256
#define BK 32
#define THREADS 512

__global__ __launch_bounds__(THREADS, 4) void gemm_fused(
    const __bf16* __restrict__ xh,
    const __bf16* __restrict__ wht,
    const float* __restrict__ bias, const float* __restrict__ gumbel,
    const int* __restrict__ flags, float* __restrict__ out) {
  __shared__ __align__(16) __bf16 Bs[2][BN * BK];  // 2 x 16 KB
  float* Ebuf = reinterpret_cast<float*>(&Bs[0][0]);  // 32 KB epilogue buffer

  const int tid  = threadIdx.x;
  const int lane = tid & 63;
  const int wave = tid >> 6;
  const int wr   = wave >> 2;      // 0..1 (M, 64 rows each)
  const int wc   = wave & 3;       // 0..3 (N, 64 cols each)
  const int fr   = lane & 15;
  const int q4   = lane >> 4;
  const int ko   = q4 * 8;         // natural A k-offset (no swizzle needed)
  const int prot8 = ((q4 + ((fr >> 1) & 3)) & 3) * 8;  // B swizzle (verified)

  // XCD swizzle: 1024 blocks; each XCD owns 8 row-panels x 16 col-panels
  const int bx  = blockIdx.x;
  const int xcd = bx & 7;
  const int ii  = bx >> 3;         // 0..127
  const int tn  = ii >> 3;         // 0..15
  const int tm  = xcd * 8 + (ii & 7);  // 0..63
  const int row0 = tm * BM;
  const int col0 = tn * BN;

  // B staging geometry (verified): chunk c -> row c>>2, phys slot c&3,
  // logical slot l = (phys - (row>>1)) & 3 (inverse of read rotation)
  const int r0 = tid >> 2;                               // 0..127
  const int l8 = (((tid & 3) - ((tid >> 3) & 3)) & 3) * 8;

  const __bf16* Bsc = wht + (size_t)col0 * D_DIM;
  // per-lane A fragment base: rows row0 + wr*64 + m*16 + fr, col ko
  const __bf16* Afr = xh + (size_t)(row0 + wr * 64 + fr) * D_DIM + ko;

  bf16x8 af0[4], af1[4];   // A fragments, double-buffered in registers

#define ALD(dst, t_)                                                         \
  do {                                                                       \
    _Pragma("unroll")                                                        \
    for (int m = 0; m < 4; ++m)                                              \
      dst[m] = *reinterpret_cast<const bf16x8*>(                             \
          Afr + (size_t)(m * 16) * D_DIM + (t_) * 32);                       \
  } while (0)

#define BGLD(b, t_)                                                          \
  do {                                                                       \
    const int ko_ = (t_) * 32;                                               \
    gld_lds16(Bsc + (size_t)r0 * D_DIM + ko_ + l8, &Bs[b][tid * 8]);         \
    gld_lds16(Bsc + (size_t)(128 + r0) * D_DIM + ko_ + l8,                   \
              &Bs[b][(512 + tid) * 8]);                                      \
  } while (0)

#define COMPUTE(b, af)                                                       \
  {                                                                          \
    bf16x8 bfr_[4];                                                          \
    _Pragma("unroll")                                                        \
    for (int n = 0; n < 4; ++n)                                              \
      bfr_[n] = *reinterpret_cast<const bf16x8*>(                            \
          &Bs[b][(wc * 64 + n * 16 + fr) * BK + prot8]);                     \
    __builtin_amdgcn_s_setprio(1);                                           \
    _Pragma("unroll")                                                        \
    for (int m = 0; m < 4; ++m) {                                            \
      _Pragma("unroll")                                                      \
      for (int n = 0; n < 4; ++n)                                            \
        acc[m][n] = MFMA(bfr_[n], af[m], acc[m][n]);                         \
    }                                                                        \
    __builtin_amdgcn_s_setprio(0);                                           \
  }

  f32x4 acc[4][4];
#pragma unroll
  for (int m = 0; m < 4; ++m)
#pragma unroll
    for (int n = 0; n < 4; ++n) acc[m][n] = (f32x4){0.f, 0.f, 0.f, 0.f};

  // prologue: A frags for t=0 into af0; B tile 0 into buf 0
  ALD(af0, 0);
  BGLD(0, 0);
  __syncthreads();

  // single-barrier loop: issue next A-frag loads + B stage, compute current.
  // COMPUTE(af0) forces only a counted vmcnt (af0's loads are oldest);
  // the barrier publishes the next B buffer.
#pragma unroll 1
  for (int it = 0; it < 15; ++it) {
    ALD(af1, 2 * it + 1); BGLD(1, 2 * it + 1);
    COMPUTE(0, af0)
    __syncthreads();
    ALD(af0, 2 * it + 2); BGLD(0, 2 * it + 2);
    COMPUTE(1, af1)
    __syncthreads();
  }
  ALD(af1, 31); BGLD(1, 31);
  COMPUTE(0, af0)
  __syncthreads();
  COMPUTE(1, af1)

  // ---- LDS-transposed epilogue (verified; nt global traffic) ----
  float* out0 = out;
  float* out1 = out + (size_t)B_DIM * N_DIM;

  const int tcol = tid & 63;            // 16B col-chunk within 256-col tile
  const int gcol = col0 + tcol * 4;
  const float4 bias4 = *reinterpret_cast<const float4*>(bias + gcol);
  const int flag = flags[(col0 >> 4) + (tcol >> 2)];

#pragma unroll
  for (int ck = 0; ck < 4; ++ck) {
    __syncthreads();   // prior chunk reads / K-loop LDS use complete
    if (wr == (ck >> 1)) {
#pragma unroll
      for (int mi = 0; mi < 2; ++mi) {
        const int lrow = mi * 16 + fr;          // 0..31
        const int m = (ck & 1) * 2 + mi;
#pragma unroll
        for (int n = 0; n < 4; ++n) {
          const int s = (wc * 16 + n * 4 + q4) ^ (lrow & 7);  // 16B slot 0..63
          *reinterpret_cast<f32x4*>(&Ebuf[lrow * 256 + s * 4]) = acc[m][n];
        }
      }
    }
    __syncthreads();
#pragma unroll
    for (int rr = 0; rr < 4; ++rr) {
      const int lrow = rr * 8 + wave;           // 0..31
      const int grow = row0 + ck * 32 + lrow;
      const f32x4 a = *reinterpret_cast<const f32x4*>(
          &Ebuf[lrow * 256 + (tcol ^ (lrow & 7)) * 4]);
      const size_t idx = (size_t)grow * N_DIM + gcol;
      const float o0 = a[0] + bias4.x;
      const float o1 = a[1] + bias4.y;
      const float o2 = a[2] + bias4.z;
      const float o3 = a[3] + bias4.w;
      f32x4 ov = {o0, o1, o2, o3};
      __builtin_nontemporal_store(ov, reinterpret_cast<f32x4*>(out0 + idx));

      f32x4 v;
      if (flag == 0) {
        const float c0 = fminf(fmaxf(o0, -15.f), 15.f);
        const float c1 = fminf(fmaxf(o1, -15.f), 15.f);
        const float c2 = fminf(fmaxf(o2, -15.f), 15.f);
        const float c3 = fminf(fmaxf(o3, -15.f), 15.f);
        const float e0 = __expf(2.f * c0), e1 = __expf(2.f * c1);
        const float e2 = __expf(2.f * c2), e3 = __expf(2.f * c3);
        v[0] = (e0 - 1.f) * fast_rcp(e0 + 1.f);
        v[1] = (e1 - 1.f) * fast_rcp(e1 + 1.f);
        v[2] = (e2 - 1.f) * fast_rcp(e2 + 1.f);
        v[3] = (e3 - 1.f) * fast_rcp(e3 + 1.f);
      } else {
        // 16-wide segment = 4 adjacent lanes: shfl_xor 1,2
        const f32x4 g = __builtin_nontemporal_load(
            reinterpret_cast<const f32x4*>(gumbel + idx));
        const float t0 = (o0 + g[0]) * TAU_INV;
        const float t1 = (o1 + g[1]) * TAU_INV;
        const float t2 = (o2 + g[2]) * TAU_INV;
        const float t3 = (o3 + g[3]) * TAU_INV;
        float mx = fmaxf(fmaxf(t0, t1), fmaxf(t2, t3));
        mx = fmaxf(mx, __shfl_xor(mx, 1));
        mx = fmaxf(mx, __shfl_xor(mx, 2));
        const float e0 = __expf(t0 - mx), e1 = __expf(t1 - mx);
        const float e2 = __expf(t2 - mx), e3 = __expf(t3 - mx);
        float s = (e0 + e1) + (e2 + e3);
        s += __shfl_xor(s, 1);
        s += __shfl_xor(s, 2);
        const float inv = fast_rcp(s);
        v[0] = e0 * inv; v[1] = e1 * inv; v[2] = e2 * inv; v[3] = e3 * inv;
      }
      __builtin_nontemporal_store(v, reinterpret_cast<f32x4*>(out1 + idx));
    }
  }
}

// ---------------------------------------------------------------------------
// fallback (only if ws_size too small): naive but correct
__global__ void fallback_kernel(const float* __restrict__ x, const float* __restrict__ W,
                                const float* __restrict__ bias, const float* __restrict__ gumbel,
                                const int* __restrict__ flags, float* __restrict__ out) {
  const size_t idx = (size_t)blockIdx.x * blockDim.x + threadIdx.x;
  const int row = (int)(idx / N_DIM);
  const int col = (int)(idx % N_DIM);
  float o = bias[col];
  const float* xr = x + (size_t)row * D_DIM;
  for (int k = 0; k < D_DIM; ++k) o += xr[k] * W[(size_t)k * N_DIM + col];
  out[idx] = o;
  float v;
  if (flags[col >> 4] == 0) {
    const float oc = fminf(fmaxf(o, -15.f), 15.f);
    const float e2 = __expf(2.f * oc);
    v = (e2 - 1.f) / (e2 + 1.f);
  } else {
    const float t = (o + gumbel[idx]) * TAU_INV;
    float mx = t;
    mx = fmaxf(mx, __shfl_xor(mx, 1));
    mx = fmaxf(mx, __shfl_xor(mx, 2));
    mx = fmaxf(mx, __shfl_xor(mx, 4));
    mx = fmaxf(mx, __shfl_xor(mx, 8));
    float e = __expf(t - mx);
    float ssum = e;
    ssum += __shfl_xor(ssum, 1);
    ssum += __shfl_xor(ssum, 2);
    ssum += __shfl_xor(ssum, 4);
    ssum += __shfl_xor(ssum, 8);
    v = e / ssum;
  }
  out[(size_t)B_DIM * N_DIM + idx] = v;
}

// ---------------------------------------------------------------------------
extern "C" void kernel_launch(void* const* d_in, const int* in_sizes, int n_in,
                              void* d_out, int out_size, void* d_ws, size_t ws_size,
                              hipStream_t stream) {
  const float* x      = (const float*)d_in[0];
  const float* W      = (const float*)d_in[1];
  const float* bias   = (const float*)d_in[2];
  const float* gumbel = (const float*)d_in[3];
  const int*   flags  = (const int*)d_in[4];
  float* out = (float*)d_out;

  const size_t xcnt = (size_t)B_DIM * D_DIM;
  const size_t wcnt = (size_t)N_DIM * D_DIM;
  const size_t need = (xcnt + wcnt) * sizeof(__bf16);  // ~24 MB

  if (ws_size < need) {
    const long long nblocks = (long long)B_DIM * N_DIM / 256;
    fallback_kernel<<<(int)nblocks, 256, 0, stream>>>(x, W, bias, gumbel, flags, out);
    return;
  }

  __bf16* xh  = (__bf16*)d_ws;
  __bf16* wht = xh + xcnt;

  prep_x<<<xcnt / 4 / 256, 256, 0, stream>>>(x, xh);
  prep_w<<<(N_DIM / 32) * (D_DIM / 32), 256, 0, stream>>>(W, wht);
  gemm_fused<<<(B_DIM / BM) * (N_DIM / BN), THREADS, 0, stream>>>(
      xh, wht, bias, gumbel, flags, out);
}

// Round 22
// 155.798 us; speedup vs baseline: 1.4876x; 1.4876x over previous
//
#include <hip/hip_runtime.h>
#include <hip/hip_bf16.h>

// Problem constants (match reference)
#define B_DIM 8192
#define D_DIM 1024
#define N_DIM 4096
#define TAU_INV 5.0f

typedef __bf16 bf16x8 __attribute__((ext_vector_type(8)));
typedef __bf16 bf16x4 __attribute__((ext_vector_type(4)));
typedef float  f32x4  __attribute__((ext_vector_type(4)));

// ---------------------------------------------------------------------------
__device__ __forceinline__ void gld_lds16(const void* g, void* l) {
  __builtin_amdgcn_global_load_lds((const __attribute__((address_space(1))) void*)g,
                                   (__attribute__((address_space(3))) void*)l,
                                   16, 0, 0);
}
__device__ __forceinline__ float fast_rcp(float x) {
  return __builtin_amdgcn_rcpf(x);
}
#define MFMA(a, b, c) __builtin_amdgcn_mfma_f32_16x16x32_bf16((a), (b), (c), 0, 0, 0)

// ---------------------------------------------------------------------------
// prep_w: W (f32 [D,N]) -> wht (bf16 [N,D]) transposed
__global__ void prep_w(const float* __restrict__ W, __bf16* __restrict__ wht) {
  __shared__ float tile[32][33];
  const int tn = blockIdx.x & 127;
  const int tk = blockIdx.x >> 7;
  const int tx = threadIdx.x & 31;
  const int ty = threadIdx.x >> 5;
#pragma unroll
  for (int r = 0; r < 4; ++r) {
    const int k = tk * 32 + ty + r * 8;
    tile[ty + r * 8][tx] = W[(size_t)k * N_DIM + tn * 32 + tx];
  }
  __syncthreads();
#pragma unroll
  for (int r = 0; r < 4; ++r) {
    const int nn = tn * 32 + ty + r * 8;
    const int kk = tk * 32 + tx;
    wht[(size_t)nn * D_DIM + kk] = (__bf16)tile[tx][ty + r * 8];
  }
}

// ---------------------------------------------------------------------------
// Fused GEMM (round-15 champion, 154.8 us): 128x256 tile, BK=32, K=1024
// single-term bf16 (absmax = comparison floor, verified round 10), 8 waves
// (2Mx4N), wave tile 64x64 (acc 64 VGPR, no spill). Single-__syncthreads-
// per-K-step double-buffer (the one barrier publishes buf t+1 AND retires
// reads of buf t); prep_x fused into staging (global f32 loads + cvt +
// ds_write; source pre-rotated, dest linear, read rotated); B via gld_lds;
// rotation swizzle (measured 0 conflicts); setprio; LDS-transposed epilogue
// with non-temporal out/gumbel traffic.
#define BM 128
#define BN 256
#define BK 32
#define THREADS 512

__global__ __launch_bounds__(THREADS, 4) void gemm_fused(
    const float* __restrict__ x,
    const __bf16* __restrict__ wht,
    const float* __restrict__ bias, const float* __restrict__ gumbel,
    const int* __restrict__ flags, float* __restrict__ out) {
  __shared__ __align__(16) __bf16 As[2][BM * BK];  // 2 x 8 KB
  __shared__ __align__(16) __bf16 Bs[2][BN * BK];  // 2 x 16 KB
  float* Ebuf = reinterpret_cast<float*>(&Bs[0][0]);  // 32 KB epilogue buffer

  const int tid  = threadIdx.x;
  const int lane = tid & 63;
  const int wave = tid >> 6;
  const int wr   = wave >> 2;      // 0..1 (M, 64 rows each)
  const int wc   = wave & 3;       // 0..3 (N, 64 cols each)
  const int fr   = lane & 15;
  const int q4   = lane >> 4;
  const int prot8 = ((q4 + ((fr >> 1) & 3)) & 3) * 8;  // verified conflict-free

  // XCD swizzle: 1024 blocks; each XCD owns 8 row-panels x 16 col-panels
  const int bx  = blockIdx.x;
  const int xcd = bx & 7;
  const int ii  = bx >> 3;         // 0..127
  const int tn  = ii >> 3;         // 0..15
  const int tm  = xcd * 8 + (ii & 7);  // 0..63
  const int row0 = tm * BM;
  const int col0 = tn * BN;

  const int r0 = tid >> 2;                               // 0..127
  const int l8 = (((tid & 3) - ((tid >> 3) & 3)) & 3) * 8;

  const float* Axf = x + (size_t)row0 * D_DIM;
  const __bf16* Bsc = wht + (size_t)col0 * D_DIM;

  f32x4 a0_, a1_;   // in-flight A registers (f32, pre-cvt)

#define ALOAD(t_)                                                            \
  do {                                                                       \
    const size_t o_ = (size_t)r0 * D_DIM + (t_) * 32 + l8;                   \
    a0_ = *reinterpret_cast<const f32x4*>(Axf + o_);                         \
    a1_ = *reinterpret_cast<const f32x4*>(Axf + o_ + 4);                     \
  } while (0)

#define CVTW(b)                                                              \
  do {                                                                       \
    bf16x8 h_;                                                               \
    h_[0] = (__bf16)a0_[0]; h_[1] = (__bf16)a0_[1];                          \
    h_[2] = (__bf16)a0_[2]; h_[3] = (__bf16)a0_[3];                          \
    h_[4] = (__bf16)a1_[0]; h_[5] = (__bf16)a1_[1];                          \
    h_[6] = (__bf16)a1_[2]; h_[7] = (__bf16)a1_[3];                          \
    *reinterpret_cast<bf16x8*>(&As[b][tid * 8]) = h_;                        \
  } while (0)

#define BGLD(b, t_)                                                          \
  do {                                                                       \
    const int ko_ = (t_) * 32;                                               \
    gld_lds16(Bsc + (size_t)r0 * D_DIM + ko_ + l8, &Bs[b][tid * 8]);         \
    gld_lds16(Bsc + (size_t)(128 + r0) * D_DIM + ko_ + l8,                   \
              &Bs[b][(512 + tid) * 8]);                                      \
  } while (0)

#define COMPUTE(b)                                                           \
  {                                                                          \
    bf16x8 bfr_[4];                                                          \
    _Pragma("unroll")                                                        \
    for (int n = 0; n < 4; ++n)                                              \
      bfr_[n] = *reinterpret_cast<const bf16x8*>(                            \
          &Bs[b][(wc * 64 + n * 16 + fr) * BK + prot8]);                     \
    __builtin_amdgcn_s_setprio(1);                                           \
    _Pragma("unroll")                                                        \
    for (int m = 0; m < 4; ++m) {                                            \
      const bf16x8 av_ = *reinterpret_cast<const bf16x8*>(                   \
          &As[b][(wr * 64 + m * 16 + fr) * BK + prot8]);                     \
      _Pragma("unroll")                                                      \
      for (int n = 0; n < 4; ++n)                                            \
        acc[m][n] = MFMA(bfr_[n], av_, acc[m][n]);                           \
    }                                                                        \
    __builtin_amdgcn_s_setprio(0);                                           \
  }

  f32x4 acc[4][4];
#pragma unroll
  for (int m = 0; m < 4; ++m)
#pragma unroll
    for (int n = 0; n < 4; ++n) acc[m][n] = (f32x4){0.f, 0.f, 0.f, 0.f};

  // prologue: stage K-tile 0 into buf 0
  ALOAD(0);
  BGLD(0, 0);
  CVTW(0);
  __syncthreads();   // drains vmcnt (B gld) + lgkmcnt (A ds_write)

  // single-barrier dbuf loop: issue stage(t+1) -> compute(t) -> A-write ->
  // one __syncthreads (publishes buf t+1, retires reads of buf t).
#pragma unroll 1
  for (int it = 0; it < 15; ++it) {
    ALOAD(2 * it + 1); BGLD(1, 2 * it + 1);
    COMPUTE(0)
    CVTW(1);
    __syncthreads();
    ALOAD(2 * it + 2); BGLD(0, 2 * it + 2);
    COMPUTE(1)
    CVTW(0);
    __syncthreads();
  }
  ALOAD(31); BGLD(1, 31);
  COMPUTE(0)
  CVTW(1);
  __syncthreads();
  COMPUTE(1)

  // ---- LDS-transposed epilogue (non-temporal global traffic) ----
  float* out0 = out;
  float* out1 = out + (size_t)B_DIM * N_DIM;

  const int tcol = tid & 63;            // 16B col-chunk within 256-col tile
  const int gcol = col0 + tcol * 4;
  const float4 bias4 = *reinterpret_cast<const float4*>(bias + gcol);
  const int flag = flags[(col0 >> 4) + (tcol >> 2)];

#pragma unroll
  for (int ck = 0; ck < 4; ++ck) {
    __syncthreads();   // prior chunk reads / K-loop LDS use complete
    if (wr == (ck >> 1)) {
#pragma unroll
      for (int mi = 0; mi < 2; ++mi) {
        const int lrow = mi * 16 + fr;          // 0..31
        const int m = (ck & 1) * 2 + mi;
#pragma unroll
        for (int n = 0; n < 4; ++n) {
          const int s = (wc * 16 + n * 4 + q4) ^ (lrow & 7);  // 16B slot 0..63
          *reinterpret_cast<f32x4*>(&Ebuf[lrow * 256 + s * 4]) = acc[m][n];
        }
      }
    }
    __syncthreads();
#pragma unroll
    for (int rr = 0; rr < 4; ++rr) {
      const int lrow = rr * 8 + wave;           // 0..31
      const int grow = row0 + ck * 32 + lrow;
      const f32x4 a = *reinterpret_cast<const f32x4*>(
          &Ebuf[lrow * 256 + (tcol ^ (lrow & 7)) * 4]);
      const size_t idx = (size_t)grow * N_DIM + gcol;
      const float o0 = a[0] + bias4.x;
      const float o1 = a[1] + bias4.y;
      const float o2 = a[2] + bias4.z;
      const float o3 = a[3] + bias4.w;
      f32x4 ov = {o0, o1, o2, o3};
      __builtin_nontemporal_store(ov, reinterpret_cast<f32x4*>(out0 + idx));

      f32x4 v;
      if (flag == 0) {
        const float c0 = fminf(fmaxf(o0, -15.f), 15.f);
        const float c1 = fminf(fmaxf(o1, -15.f), 15.f);
        const float c2 = fminf(fmaxf(o2, -15.f), 15.f);
        const float c3 = fminf(fmaxf(o3, -15.f), 15.f);
        const float e0 = __expf(2.f * c0), e1 = __expf(2.f * c1);
        const float e2 = __expf(2.f * c2), e3 = __expf(2.f * c3);
        v[0] = (e0 - 1.f) * fast_rcp(e0 + 1.f);
        v[1] = (e1 - 1.f) * fast_rcp(e1 + 1.f);
        v[2] = (e2 - 1.f) * fast_rcp(e2 + 1.f);
        v[3] = (e3 - 1.f) * fast_rcp(e3 + 1.f);
      } else {
        // 16-wide segment = 4 adjacent lanes: shfl_xor 1,2
        const f32x4 g = __builtin_nontemporal_load(
            reinterpret_cast<const f32x4*>(gumbel + idx));
        const float t0 = (o0 + g[0]) * TAU_INV;
        const float t1 = (o1 + g[1]) * TAU_INV;
        const float t2 = (o2 + g[2]) * TAU_INV;
        const float t3 = (o3 + g[3]) * TAU_INV;
        float mx = fmaxf(fmaxf(t0, t1), fmaxf(t2, t3));
        mx = fmaxf(mx, __shfl_xor(mx, 1));
        mx = fmaxf(mx, __shfl_xor(mx, 2));
        const float e0 = __expf(t0 - mx), e1 = __expf(t1 - mx);
        const float e2 = __expf(t2 - mx), e3 = __expf(t3 - mx);
        float s = (e0 + e1) + (e2 + e3);
        s += __shfl_xor(s, 1);
        s += __shfl_xor(s, 2);
        const float inv = fast_rcp(s);
        v[0] = e0 * inv; v[1] = e1 * inv; v[2] = e2 * inv; v[3] = e3 * inv;
      }
      __builtin_nontemporal_store(v, reinterpret_cast<f32x4*>(out1 + idx));
    }
  }
}

// ---------------------------------------------------------------------------
// fallback (only if ws_size too small): naive but correct
__global__ void fallback_kernel(const float* __restrict__ x, const float* __restrict__ W,
                                const float* __restrict__ bias, const float* __restrict__ gumbel,
                                const int* __restrict__ flags, float* __restrict__ out) {
  const size_t idx = (size_t)blockIdx.x * blockDim.x + threadIdx.x;
  const int row = (int)(idx / N_DIM);
  const int col = (int)(idx % N_DIM);
  float o = bias[col];
  const float* xr = x + (size_t)row * D_DIM;
  for (int k = 0; k < D_DIM; ++k) o += xr[k] * W[(size_t)k * N_DIM + col];
  out[idx] = o;
  float v;
  if (flags[col >> 4] == 0) {
    const float oc = fminf(fmaxf(o, -15.f), 15.f);
    const float e2 = __expf(2.f * oc);
    v = (e2 - 1.f) / (e2 + 1.f);
  } else {
    const float t = (o + gumbel[idx]) * TAU_INV;
    float mx = t;
    mx = fmaxf(mx, __shfl_xor(mx, 1));
    mx = fmaxf(mx, __shfl_xor(mx, 2));
    mx = fmaxf(mx, __shfl_xor(mx, 4));
    mx = fmaxf(mx, __shfl_xor(mx, 8));
    float e = __expf(t - mx);
    float ssum = e;
    ssum += __shfl_xor(ssum, 1);
    ssum += __shfl_xor(ssum, 2);
    ssum += __shfl_xor(ssum, 4);
    ssum += __shfl_xor(ssum, 8);
    v = e / ssum;
  }
  out[(size_t)B_DIM * N_DIM + idx] = v;
}

// ---------------------------------------------------------------------------
extern "C" void kernel_launch(void* const* d_in, const int* in_sizes, int n_in,
                              void* d_out, int out_size, void* d_ws, size_t ws_size,
                              hipStream_t stream) {
  const float* x      = (const float*)d_in[0];
  const float* W      = (const float*)d_in[1];
  const float* bias   = (const float*)d_in[2];
  const float* gumbel = (const float*)d_in[3];
  const int*   flags  = (const int*)d_in[4];
  float* out = (float*)d_out;

  const size_t wcnt = (size_t)N_DIM * D_DIM;
  const size_t need = wcnt * sizeof(__bf16);  // ~8 MB

  if (ws_size < need) {
    const long long nblocks = (long long)B_DIM * N_DIM / 256;
    fallback_kernel<<<(int)nblocks, 256, 0, stream>>>(x, W, bias, gumbel, flags, out);
    return;
  }

  __bf16* wht = (__bf16*)d_ws;

  prep_w<<<(N_DIM / 32) * (D_DIM / 32), 256, 0, stream>>>(W, wht);
  gemm_fused<<<(B_DIM / BM) * (N_DIM / BN), THREADS, 0, stream>>>(
      x, wht, bias, gumbel, flags, out);
}